// Round 4
// baseline (435.995 us; speedup 1.0000x reference)
//
#include <hip/hip_runtime.h>

#define PRE   1024
#define POST  1024
#define BATCH 256
#define HIST  50
#define NPAIR (PRE * POST)

typedef float nf4 __attribute__((ext_vector_type(4)));   // native vec for nontemporal builtins

// ---------------- kernel 1: batch means + EMA ----------------
// 128 blocks (64 per matrix), 16 cols each: 4x the CUs engaged vs the old
// 32-block version (was latency-bound on 64 strided loads/thread).
#define MCOLS 16
__global__ __launch_bounds__(256) void means_kernel(
    const float* __restrict__ pre_spikes,   // [BATCH, PRE]
    const float* __restrict__ post_spikes,  // [BATCH, POST]
    const float* __restrict__ pre_activity, // [PRE]
    const float* __restrict__ post_activity,// [POST]
    float* __restrict__ ws_means,           // [PRE + POST] scratch
    float* __restrict__ out_pre_act,        // [PRE]
    float* __restrict__ out_post_act)       // [POST]
{
    __shared__ float red[256];
    int tid = threadIdx.x;
    int blk = blockIdx.x;                  // 0..127
    bool is_pre = blk < 64;
    const float* mat = is_pre ? pre_spikes : post_spikes;
    const float* act = is_pre ? pre_activity : post_activity;
    float* out_act   = is_pre ? out_pre_act : out_post_act;
    float* ws        = is_pre ? ws_means : ws_means + PRE;
    int col0 = (blk & 63) * MCOLS;

    int col = col0 + (tid & 15);
    int chunk = tid >> 4;                  // 0..15, 16 rows each
    float s = 0.f;
#pragma unroll
    for (int r = chunk * 16; r < chunk * 16 + 16; ++r)
        s += mat[r * 1024 + col];
    red[tid] = s;
    __syncthreads();
    if (tid < 16) {
        float t = 0.f;
#pragma unroll
        for (int k = 0; k < 16; ++k)
            t += red[k * 16 + tid];
        float m = t * (1.0f / BATCH);
        int c = col0 + tid;
        ws[c] = m;
        out_act[c] = 0.99f * act[c] + 0.01f * m;
    }
}

// ---------------- kernel 2: masked SGEMM, 64x64 tile, 4x4/thread, split-K x8 ----------------
#define GBM 64
#define GBN 64
#define GBK 16
#define GKSPLIT 8
#define GLD 68                      // padded leading dim for As/Bs
__global__ __launch_bounds__(256) void gemm_kernel(
    const float* __restrict__ A,   // [BATCH, PRE]
    const float* __restrict__ W,   // [PRE, POST]
    const float* __restrict__ Mk,  // [PRE, POST]
    float* __restrict__ C)         // [BATCH, POST]
{
    __shared__ __align__(16) float As[GBK * GLD];   // As[k][m] (transposed)
    __shared__ __align__(16) float Bs[GBK * GLD];   // Bs[k][n]
    int tid = threadIdx.x;
    int bn = blockIdx.x;           // 0..15 col tile
    int bm = blockIdx.y;           // 0..3  row tile
    int bz = blockIdx.z;           // 0..7  k split
    int kbase = bz * (PRE / GKSPLIT);

    int ar = tid >> 2;
    int ak = (tid & 3) << 2;
    int bk = tid >> 4;
    int bn4 = (tid & 15) << 2;
    int tn4 = (tid & 15) << 2;
    int tm4 = (tid >> 4) << 2;

    const float* Ap = &A[(bm * GBM + ar) * PRE + kbase + ak];
    const float* Wp = &W [(size_t)(kbase + bk) * POST + bn * GBN + bn4];
    const float* Mp = &Mk[(size_t)(kbase + bk) * POST + bn * GBN + bn4];

    float acc[4][4] = {};

    for (int k0 = 0; k0 < PRE / GKSPLIT; k0 += GBK) {
        float4 av = *(const float4*)(Ap + k0);
        float4 wv = *(const float4*)(Wp + (size_t)k0 * POST);
        float4 mv = *(const float4*)(Mp + (size_t)k0 * POST);
        wv.x *= mv.x; wv.y *= mv.y; wv.z *= mv.z; wv.w *= mv.w;
        __syncthreads();                       // protect previous iter's reads
        As[(ak + 0) * GLD + ar] = av.x;
        As[(ak + 1) * GLD + ar] = av.y;
        As[(ak + 2) * GLD + ar] = av.z;
        As[(ak + 3) * GLD + ar] = av.w;
        *(float4*)&Bs[bk * GLD + bn4] = wv;
        __syncthreads();
#pragma unroll
        for (int kk = 0; kk < GBK; ++kk) {
            float4 a4 = *(const float4*)&As[kk * GLD + tm4];
            float4 b4 = *(const float4*)&Bs[kk * GLD + tn4];
            const float* ap = (const float*)&a4;
            const float* bp = (const float*)&b4;
#pragma unroll
            for (int i = 0; i < 4; ++i)
#pragma unroll
                for (int j = 0; j < 4; ++j)
                    acc[i][j] += ap[i] * bp[j];
        }
    }
#pragma unroll
    for (int i = 0; i < 4; ++i)
#pragma unroll
        for (int j = 0; j < 4; ++j)
            atomicAdd(&C[(size_t)(bm * GBM + tm4 + i) * POST + bn * GBN + tn4 + j],
                      acc[i][j]);
}

// ---------------- kernel 3: history copy + in-flight scatter + fused mean ----------------
// 128 pairs/block (6400 floats = 1600 float4), 320 threads, 5 float4/thread.
// THIS ROUND: the 25.6 KB LDS tile + serial 25x ds_read_b64 tail is replaced
// by a 128-float psum[] accumulated with ds_add_f32 DURING the copy loop --
// the avg reduction now overlaps the streaming copy instead of serializing
// after a vmcnt(0)-draining barrier. corr (ws_means gather) is computed only
// for the ~8% of float4s that actually contain the slot-idx element.
// Layout facts used: r0 = 4*fl is even -> t0 = r0%50 is even, <= 48; a
// straddling float4 has t0 == 48 exactly (2/2 component split), and d2 < 4
// implies t0 == 48.
#define PPB 128
#define HTHREADS 320
#define NIT 5                      // 1600 / 320
__global__ __launch_bounds__(HTHREADS) void history_kernel(
    const float* __restrict__ hist_in,    // [PRE, POST, HIST]
    const int*   __restrict__ corr_index, // scalar
    const float* __restrict__ ws_means,   // [PRE + POST]
    float* __restrict__ hist_out,         // [PRE, POST, HIST]
    float* __restrict__ avg_out)          // [PRE, POST]
{
    __shared__ float psum[PPB];
    int tid = threadIdx.x;
    int p0 = blockIdx.x * PPB;
    int idx = ((corr_index[0] % HIST) + HIST) % HIST;

    if (tid < PPB) psum[tid] = 0.f;

    const nf4* in4  = (const nf4*)(hist_in + (size_t)p0 * HIST);
    nf4*       out4 = (nf4*)(hist_out + (size_t)p0 * HIST);

    nf4 v[NIT];
#pragma unroll
    for (int it = 0; it < NIT; ++it)
        v[it] = __builtin_nontemporal_load(&in4[it * HTHREADS + tid]);

    __syncthreads();                       // psum init visible

#pragma unroll
    for (int it = 0; it < NIT; ++it) {
        int fl = it * HTHREADS + tid;
        int r0 = 4 * fl;               // relative float index of component 0
        int pl = r0 / HIST;            // local pair of component 0
        int t0 = r0 - pl * HIST;       // slot of component 0 (even, 0..48)
        int d  = idx - t0;             // component holding slot idx (pair pl)
        int d2 = idx + HIST - t0;      // component holding slot idx (pair pl+1), >= 2
        bool strad = (t0 == 48);
        bool needA = ((unsigned)d) < 4u;
        bool needB = (d2 < 4);         // implies strad
        float corr = 0.f;
        if (needA | needB) {           // rare: ~8% of float4s
            int pair = needA ? (p0 + pl) : (p0 + pl + 1);
            corr = ws_means[pair >> 10] * ws_means[PRE + (pair & (POST - 1))];
        }
        nf4 w = v[it];
        w.x = (d == 0) ? corr : w.x;
        w.y = (d == 1) ? corr : w.y;
        w.z = (d == 2 || d2 == 2) ? corr : w.z;
        w.w = (d == 3 || d2 == 3) ? corr : w.w;
        __builtin_nontemporal_store(w, &out4[fl]);

        float slo = w.x + w.y;         // slots t0, t0+1   (always pair pl)
        float shi = w.z + w.w;         // slots t0+2, t0+3 (pair pl+1 iff strad)
        if (strad) {
            atomicAdd(&psum[pl], slo);
            atomicAdd(&psum[pl + 1], shi);
        } else {
            atomicAdd(&psum[pl], slo + shi);
        }
    }
    __syncthreads();

    if (tid < PPB)
        __builtin_nontemporal_store(psum[tid] * (1.0f / HIST), &avg_out[p0 + tid]);
}

extern "C" void kernel_launch(void* const* d_in, const int* in_sizes, int n_in,
                              void* d_out, int out_size, void* d_ws, size_t ws_size,
                              hipStream_t stream)
{
    const float* pre_spikes  = (const float*)d_in[0];
    const float* post_spikes = (const float*)d_in[1];
    const float* W           = (const float*)d_in[2];
    const float* Mk          = (const float*)d_in[3];
    const float* hist        = (const float*)d_in[4];
    const float* pre_act     = (const float*)d_in[5];
    const float* post_act    = (const float*)d_in[6];
    const int*   corr_index  = (const int*)d_in[7];

    float* out = (float*)d_out;
    float* out_current  = out;                          // [256,1024]   262144
    float* out_pre_act  = out + 262144;                 // [1024]
    float* out_post_act = out + 263168;                 // [1024]
    float* out_avg      = out + 264192;                 // [1024,1024]  1048576
    float* out_hist     = out + 1312768;                // [1024,1024,50]

    float* ws_means = (float*)d_ws;                     // 2048 floats

    means_kernel<<<128, 256, 0, stream>>>(
        pre_spikes, post_spikes, pre_act, post_act,
        ws_means, out_pre_act, out_post_act);

    (void)hipMemsetAsync(out_current, 0, (size_t)BATCH * POST * sizeof(float), stream);

    gemm_kernel<<<dim3(POST / GBN, BATCH / GBM, GKSPLIT), 256, 0, stream>>>(
        pre_spikes, W, Mk, out_current);

    history_kernel<<<NPAIR / PPB, HTHREADS, 0, stream>>>(
        hist, corr_index, ws_means, out_hist, out_avg);
}

// Round 5
// 405.171 us; speedup vs baseline: 1.0761x; 1.0761x over previous
//
#include <hip/hip_runtime.h>

#define PRE   1024
#define POST  1024
#define BATCH 256
#define HIST  50
#define NPAIR (PRE * POST)

typedef float nf4 __attribute__((ext_vector_type(4)));   // native vec for nontemporal builtins

// ---------------- kernel 1: batch means + EMA ----------------
// 128 blocks (64 per matrix), 16 cols each: 4x the CUs engaged vs the old
// 32-block version.
#define MCOLS 16
__global__ __launch_bounds__(256) void means_kernel(
    const float* __restrict__ pre_spikes,   // [BATCH, PRE]
    const float* __restrict__ post_spikes,  // [BATCH, POST]
    const float* __restrict__ pre_activity, // [PRE]
    const float* __restrict__ post_activity,// [POST]
    float* __restrict__ ws_means,           // [PRE + POST] scratch
    float* __restrict__ out_pre_act,        // [PRE]
    float* __restrict__ out_post_act)       // [POST]
{
    __shared__ float red[256];
    int tid = threadIdx.x;
    int blk = blockIdx.x;                  // 0..127
    bool is_pre = blk < 64;
    const float* mat = is_pre ? pre_spikes : post_spikes;
    const float* act = is_pre ? pre_activity : post_activity;
    float* out_act   = is_pre ? out_pre_act : out_post_act;
    float* ws        = is_pre ? ws_means : ws_means + PRE;
    int col0 = (blk & 63) * MCOLS;

    int col = col0 + (tid & 15);
    int chunk = tid >> 4;                  // 0..15, 16 rows each
    float s = 0.f;
#pragma unroll
    for (int r = chunk * 16; r < chunk * 16 + 16; ++r)
        s += mat[r * 1024 + col];
    red[tid] = s;
    __syncthreads();
    if (tid < 16) {
        float t = 0.f;
#pragma unroll
        for (int k = 0; k < 16; ++k)
            t += red[k * 16 + tid];
        float m = t * (1.0f / BATCH);
        int c = col0 + tid;
        ws[c] = m;
        out_act[c] = 0.99f * act[c] + 0.01f * m;
    }
}

// ---------------- kernel 2: masked SGEMM, 64x64 tile, 4x4/thread, split-K x8 ----------------
#define GBM 64
#define GBN 64
#define GBK 16
#define GKSPLIT 8
#define GLD 68                      // padded leading dim for As/Bs
__global__ __launch_bounds__(256) void gemm_kernel(
    const float* __restrict__ A,   // [BATCH, PRE]
    const float* __restrict__ W,   // [PRE, POST]
    const float* __restrict__ Mk,  // [PRE, POST]
    float* __restrict__ C)         // [BATCH, POST]
{
    __shared__ __align__(16) float As[GBK * GLD];   // As[k][m] (transposed)
    __shared__ __align__(16) float Bs[GBK * GLD];   // Bs[k][n]
    int tid = threadIdx.x;
    int bn = blockIdx.x;           // 0..15 col tile
    int bm = blockIdx.y;           // 0..3  row tile
    int bz = blockIdx.z;           // 0..7  k split
    int kbase = bz * (PRE / GKSPLIT);

    int ar = tid >> 2;
    int ak = (tid & 3) << 2;
    int bk = tid >> 4;
    int bn4 = (tid & 15) << 2;
    int tn4 = (tid & 15) << 2;
    int tm4 = (tid >> 4) << 2;

    const float* Ap = &A[(bm * GBM + ar) * PRE + kbase + ak];
    const float* Wp = &W [(size_t)(kbase + bk) * POST + bn * GBN + bn4];
    const float* Mp = &Mk[(size_t)(kbase + bk) * POST + bn * GBN + bn4];

    float acc[4][4] = {};

    for (int k0 = 0; k0 < PRE / GKSPLIT; k0 += GBK) {
        float4 av = *(const float4*)(Ap + k0);
        float4 wv = *(const float4*)(Wp + (size_t)k0 * POST);
        float4 mv = *(const float4*)(Mp + (size_t)k0 * POST);
        wv.x *= mv.x; wv.y *= mv.y; wv.z *= mv.z; wv.w *= mv.w;
        __syncthreads();                       // protect previous iter's reads
        As[(ak + 0) * GLD + ar] = av.x;
        As[(ak + 1) * GLD + ar] = av.y;
        As[(ak + 2) * GLD + ar] = av.z;
        As[(ak + 3) * GLD + ar] = av.w;
        *(float4*)&Bs[bk * GLD + bn4] = wv;
        __syncthreads();
#pragma unroll
        for (int kk = 0; kk < GBK; ++kk) {
            float4 a4 = *(const float4*)&As[kk * GLD + tm4];
            float4 b4 = *(const float4*)&Bs[kk * GLD + tn4];
            const float* ap = (const float*)&a4;
            const float* bp = (const float*)&b4;
#pragma unroll
            for (int i = 0; i < 4; ++i)
#pragma unroll
                for (int j = 0; j < 4; ++j)
                    acc[i][j] += ap[i] * bp[j];
        }
    }
#pragma unroll
    for (int i = 0; i < 4; ++i)
#pragma unroll
        for (int j = 0; j < 4; ++j)
            atomicAdd(&C[(size_t)(bm * GBM + tm4 + i) * POST + bn * GBN + tn4 + j],
                      acc[i][j]);
}

// ---------------- kernel 3: history copy + in-flight scatter + mean ----------------
// 128 pairs/block (6400 floats = 1600 float4), 320 threads, 5 float4/thread.
// R5 structure (revert of R4's LDS-atomic regression, which serialized ~13
// same-address ds_add per wave):
//   nt loads -> substitute -> LDS tile writes -> __syncthreads ->
//   nt global stores (fire-and-forget) -> 128-thread tail reduce.
// Key fix vs R3: global stores are issued AFTER the barrier, so the
// barrier's implicit vmcnt(0) drain no longer waits on 160 KB of HBM
// stores before the tail can start; the tail reduce now overlaps the
// in-flight stores. corr gather is conditional (~8% of float4s).
#define PPB 128
#define HTHREADS 320
#define NIT 5                      // 1600 / 320
__global__ __launch_bounds__(HTHREADS) void history_kernel(
    const float* __restrict__ hist_in,    // [PRE, POST, HIST]
    const int*   __restrict__ corr_index, // scalar
    const float* __restrict__ ws_means,   // [PRE + POST]
    float* __restrict__ hist_out,         // [PRE, POST, HIST]
    float* __restrict__ avg_out)          // [PRE, POST]
{
    __shared__ __align__(16) float tile[PPB * HIST];   // 25600 B
    int tid = threadIdx.x;
    int p0 = blockIdx.x * PPB;
    int idx = ((corr_index[0] % HIST) + HIST) % HIST;

    const nf4* in4   = (const nf4*)(hist_in + (size_t)p0 * HIST);
    nf4*       out4  = (nf4*)(hist_out + (size_t)p0 * HIST);
    nf4*       tile4 = (nf4*)tile;

    nf4 v[NIT];
#pragma unroll
    for (int it = 0; it < NIT; ++it)
        v[it] = __builtin_nontemporal_load(&in4[it * HTHREADS + tid]);

#pragma unroll
    for (int it = 0; it < NIT; ++it) {
        int fl = it * HTHREADS + tid;
        int r0 = 4 * fl;               // relative float index of component 0
        int pl = r0 / HIST;            // local pair of component 0
        int t0 = r0 - pl * HIST;       // slot of component 0 (even, 0..48)
        int d  = idx - t0;             // component holding slot idx (pair pl)
        int d2 = idx + HIST - t0;      // component holding slot idx (pair pl+1), >= 2
        bool needA = ((unsigned)d) < 4u;
        bool needB = (d2 < 4);         // implies t0 == 48; disjoint from needA
        float corr = 0.f;
        if (needA | needB) {           // rare: ~8% of float4s
            int pair = needA ? (p0 + pl) : (p0 + pl + 1);
            corr = ws_means[pair >> 10] * ws_means[PRE + (pair & (POST - 1))];
        }
        nf4 w = v[it];
        w.x = (d == 0) ? corr : w.x;
        w.y = (d == 1) ? corr : w.y;
        w.z = (d == 2 || d2 == 2) ? corr : w.z;
        w.w = (d == 3 || d2 == 3) ? corr : w.w;
        v[it] = w;                     // keep for the post-barrier store
        tile4[fl] = w;
    }
    __syncthreads();                   // only LDS writes outstanding here

#pragma unroll
    for (int it = 0; it < NIT; ++it)
        __builtin_nontemporal_store(v[it], &out4[it * HTHREADS + tid]);

    if (tid < PPB) {
        int pair = p0 + tid;
        const float2* tp = (const float2*)&tile[tid * HIST];
        float s = 0.f;
#pragma unroll
        for (int k = 0; k < HIST / 2; ++k) {
            float2 w = tp[k];
            s += w.x + w.y;
        }
        __builtin_nontemporal_store(s * (1.0f / HIST), &avg_out[pair]);
    }
}

extern "C" void kernel_launch(void* const* d_in, const int* in_sizes, int n_in,
                              void* d_out, int out_size, void* d_ws, size_t ws_size,
                              hipStream_t stream)
{
    const float* pre_spikes  = (const float*)d_in[0];
    const float* post_spikes = (const float*)d_in[1];
    const float* W           = (const float*)d_in[2];
    const float* Mk          = (const float*)d_in[3];
    const float* hist        = (const float*)d_in[4];
    const float* pre_act     = (const float*)d_in[5];
    const float* post_act    = (const float*)d_in[6];
    const int*   corr_index  = (const int*)d_in[7];

    float* out = (float*)d_out;
    float* out_current  = out;                          // [256,1024]   262144
    float* out_pre_act  = out + 262144;                 // [1024]
    float* out_post_act = out + 263168;                 // [1024]
    float* out_avg      = out + 264192;                 // [1024,1024]  1048576
    float* out_hist     = out + 1312768;                // [1024,1024,50]

    float* ws_means = (float*)d_ws;                     // 2048 floats

    means_kernel<<<128, 256, 0, stream>>>(
        pre_spikes, post_spikes, pre_act, post_act,
        ws_means, out_pre_act, out_post_act);

    (void)hipMemsetAsync(out_current, 0, (size_t)BATCH * POST * sizeof(float), stream);

    gemm_kernel<<<dim3(POST / GBN, BATCH / GBM, GKSPLIT), 256, 0, stream>>>(
        pre_spikes, W, Mk, out_current);

    history_kernel<<<NPAIR / PPB, HTHREADS, 0, stream>>>(
        hist, corr_index, ws_means, out_hist, out_avg);
}

// Round 6
// 373.373 us; speedup vs baseline: 1.1677x; 1.0852x over previous
//
#include <hip/hip_runtime.h>

#define PRE   1024
#define POST  1024
#define BATCH 256
#define HIST  50
#define NPAIR (PRE * POST)

typedef float nf4 __attribute__((ext_vector_type(4)));   // native vec for nontemporal builtins

// ---------------- kernel 1: batch means + EMA ----------------
// 128 blocks (64 per matrix), 16 cols each.
#define MCOLS 16
__global__ __launch_bounds__(256) void means_kernel(
    const float* __restrict__ pre_spikes,   // [BATCH, PRE]
    const float* __restrict__ post_spikes,  // [BATCH, POST]
    const float* __restrict__ pre_activity, // [PRE]
    const float* __restrict__ post_activity,// [POST]
    float* __restrict__ ws_means,           // [PRE + POST] scratch
    float* __restrict__ out_pre_act,        // [PRE]
    float* __restrict__ out_post_act)       // [POST]
{
    __shared__ float red[256];
    int tid = threadIdx.x;
    int blk = blockIdx.x;                  // 0..127
    bool is_pre = blk < 64;
    const float* mat = is_pre ? pre_spikes : post_spikes;
    const float* act = is_pre ? pre_activity : post_activity;
    float* out_act   = is_pre ? out_pre_act : out_post_act;
    float* ws        = is_pre ? ws_means : ws_means + PRE;
    int col0 = (blk & 63) * MCOLS;

    int col = col0 + (tid & 15);
    int chunk = tid >> 4;                  // 0..15, 16 rows each
    float s = 0.f;
#pragma unroll
    for (int r = chunk * 16; r < chunk * 16 + 16; ++r)
        s += mat[r * 1024 + col];
    red[tid] = s;
    __syncthreads();
    if (tid < 16) {
        float t = 0.f;
#pragma unroll
        for (int k = 0; k < 16; ++k)
            t += red[k * 16 + tid];
        float m = t * (1.0f / BATCH);
        int c = col0 + tid;
        ws[c] = m;
        out_act[c] = 0.99f * act[c] + 0.01f * m;
    }
}

// ---------------- kernel 2: masked SGEMM, 64x64 tile, 4x4/thread, split-K x8 ----------------
// R6: epilogue writes per-split partials to workspace with plain dwordx4
// stores (use_part=1) instead of 2.1M device-scope float atomics into 1M
// addresses (cross-XCD atomics resolve at a common point; each C address was
// RMW'd 8x). A reduce kernel folds the 8 slices. Atomic path kept as
// fallback when ws is too small.
#define GBM 64
#define GBN 64
#define GBK 16
#define GKSPLIT 8
#define GLD 68                      // padded leading dim for As/Bs
__global__ __launch_bounds__(256) void gemm_kernel(
    const float* __restrict__ A,   // [BATCH, PRE]
    const float* __restrict__ W,   // [PRE, POST]
    const float* __restrict__ Mk,  // [PRE, POST]
    float* __restrict__ C,         // [BATCH, POST] (atomic path)
    float* __restrict__ Cpart,     // [GKSPLIT, BATCH*POST] (partial path)
    int use_part)
{
    __shared__ __align__(16) float As[GBK * GLD];   // As[k][m] (transposed)
    __shared__ __align__(16) float Bs[GBK * GLD];   // Bs[k][n]
    int tid = threadIdx.x;
    int bn = blockIdx.x;           // 0..15 col tile
    int bm = blockIdx.y;           // 0..3  row tile
    int bz = blockIdx.z;           // 0..7  k split
    int kbase = bz * (PRE / GKSPLIT);

    int ar = tid >> 2;
    int ak = (tid & 3) << 2;
    int bk = tid >> 4;
    int bn4 = (tid & 15) << 2;
    int tn4 = (tid & 15) << 2;
    int tm4 = (tid >> 4) << 2;

    const float* Ap = &A[(bm * GBM + ar) * PRE + kbase + ak];
    const float* Wp = &W [(size_t)(kbase + bk) * POST + bn * GBN + bn4];
    const float* Mp = &Mk[(size_t)(kbase + bk) * POST + bn * GBN + bn4];

    float acc[4][4] = {};

    for (int k0 = 0; k0 < PRE / GKSPLIT; k0 += GBK) {
        float4 av = *(const float4*)(Ap + k0);
        float4 wv = *(const float4*)(Wp + (size_t)k0 * POST);
        float4 mv = *(const float4*)(Mp + (size_t)k0 * POST);
        wv.x *= mv.x; wv.y *= mv.y; wv.z *= mv.z; wv.w *= mv.w;
        __syncthreads();                       // protect previous iter's reads
        As[(ak + 0) * GLD + ar] = av.x;
        As[(ak + 1) * GLD + ar] = av.y;
        As[(ak + 2) * GLD + ar] = av.z;
        As[(ak + 3) * GLD + ar] = av.w;
        *(float4*)&Bs[bk * GLD + bn4] = wv;
        __syncthreads();
#pragma unroll
        for (int kk = 0; kk < GBK; ++kk) {
            float4 a4 = *(const float4*)&As[kk * GLD + tm4];
            float4 b4 = *(const float4*)&Bs[kk * GLD + tn4];
            const float* ap = (const float*)&a4;
            const float* bp = (const float*)&b4;
#pragma unroll
            for (int i = 0; i < 4; ++i)
#pragma unroll
                for (int j = 0; j < 4; ++j)
                    acc[i][j] += ap[i] * bp[j];
        }
    }
    if (use_part) {
        float* dst = &Cpart[(size_t)bz * (BATCH * POST)
                            + (size_t)(bm * GBM + tm4) * POST + bn * GBN + tn4];
#pragma unroll
        for (int i = 0; i < 4; ++i) {
            float4 r; r.x = acc[i][0]; r.y = acc[i][1]; r.z = acc[i][2]; r.w = acc[i][3];
            *(float4*)(dst + (size_t)i * POST) = r;
        }
    } else {
#pragma unroll
        for (int i = 0; i < 4; ++i)
#pragma unroll
            for (int j = 0; j < 4; ++j)
                atomicAdd(&C[(size_t)(bm * GBM + tm4 + i) * POST + bn * GBN + tn4 + j],
                          acc[i][j]);
    }
}

// reduce: C[i] = sum_z Cpart[z][i], float4-vectorized. 256 blocks x 256 thr.
__global__ __launch_bounds__(256) void gemm_reduce_kernel(
    const float* __restrict__ Cpart,   // [GKSPLIT, BATCH*POST]
    float* __restrict__ C)             // [BATCH*POST]
{
    int g = blockIdx.x * 256 + threadIdx.x;     // 0..65535 float4 index
    const nf4* p4 = (const nf4*)Cpart;
    nf4 s = p4[g];
#pragma unroll
    for (int z = 1; z < GKSPLIT; ++z)
        s += p4[(size_t)z * (BATCH * POST / 4) + g];
    ((nf4*)C)[g] = s;
}

// ---------------- kernel 3: history copy + in-flight scatter + mean ----------------
// R5-proven structure: nt loads -> substitute -> LDS tile writes ->
// __syncthreads -> nt global stores (fire-and-forget) -> tail reduce.
// R6: tail parallelized 2 threads/pair (even/odd float2 interleave, uniform
// 13-iter guarded loop, shfl_xor(1) combine) -- halves the 25-deep serial
// add chain. tile padded +2 floats for the guarded over-read of the last pair.
#define PPB 128
#define HTHREADS 320
#define NIT 5                      // 1600 / 320
__global__ __launch_bounds__(HTHREADS) void history_kernel(
    const float* __restrict__ hist_in,    // [PRE, POST, HIST]
    const int*   __restrict__ corr_index, // scalar
    const float* __restrict__ ws_means,   // [PRE + POST]
    float* __restrict__ hist_out,         // [PRE, POST, HIST]
    float* __restrict__ avg_out)          // [PRE, POST]
{
    __shared__ __align__(16) float tile[PPB * HIST + 2];   // +2: guarded tail over-read
    int tid = threadIdx.x;
    int p0 = blockIdx.x * PPB;
    int idx = ((corr_index[0] % HIST) + HIST) % HIST;

    const nf4* in4   = (const nf4*)(hist_in + (size_t)p0 * HIST);
    nf4*       out4  = (nf4*)(hist_out + (size_t)p0 * HIST);
    nf4*       tile4 = (nf4*)tile;

    nf4 v[NIT];
#pragma unroll
    for (int it = 0; it < NIT; ++it)
        v[it] = __builtin_nontemporal_load(&in4[it * HTHREADS + tid]);

#pragma unroll
    for (int it = 0; it < NIT; ++it) {
        int fl = it * HTHREADS + tid;
        int r0 = 4 * fl;               // relative float index of component 0
        int pl = r0 / HIST;            // local pair of component 0
        int t0 = r0 - pl * HIST;       // slot of component 0 (even, 0..48)
        int d  = idx - t0;             // component holding slot idx (pair pl)
        int d2 = idx + HIST - t0;      // component holding slot idx (pair pl+1), >= 2
        bool needA = ((unsigned)d) < 4u;
        bool needB = (d2 < 4);         // implies t0 == 48; disjoint from needA
        float corr = 0.f;
        if (needA | needB) {           // rare: ~8% of float4s
            int pair = needA ? (p0 + pl) : (p0 + pl + 1);
            corr = ws_means[pair >> 10] * ws_means[PRE + (pair & (POST - 1))];
        }
        nf4 w = v[it];
        w.x = (d == 0) ? corr : w.x;
        w.y = (d == 1) ? corr : w.y;
        w.z = (d == 2 || d2 == 2) ? corr : w.z;
        w.w = (d == 3 || d2 == 3) ? corr : w.w;
        v[it] = w;                     // keep for the post-barrier store
        tile4[fl] = w;
    }
    __syncthreads();                   // only LDS writes outstanding here

#pragma unroll
    for (int it = 0; it < NIT; ++it)
        __builtin_nontemporal_store(v[it], &out4[it * HTHREADS + tid]);

    if (tid < 2 * PPB) {
        int pl   = tid >> 1;
        int half = tid & 1;
        const float2* tp = (const float2*)&tile[pl * HIST];
        float s = 0.f;
#pragma unroll
        for (int k = 0; k < 13; ++k) {         // float2 indices half, half+2, ...
            int f2 = 2 * k + half;
            float2 w = tp[f2];                 // f2==25 over-read lands in pad
            if (f2 < 25) s += w.x + w.y;
        }
        s += __shfl_xor(s, 1);
        if (half == 0)
            __builtin_nontemporal_store(s * (1.0f / HIST), &avg_out[p0 + pl]);
    }
}

extern "C" void kernel_launch(void* const* d_in, const int* in_sizes, int n_in,
                              void* d_out, int out_size, void* d_ws, size_t ws_size,
                              hipStream_t stream)
{
    const float* pre_spikes  = (const float*)d_in[0];
    const float* post_spikes = (const float*)d_in[1];
    const float* W           = (const float*)d_in[2];
    const float* Mk          = (const float*)d_in[3];
    const float* hist        = (const float*)d_in[4];
    const float* pre_act     = (const float*)d_in[5];
    const float* post_act    = (const float*)d_in[6];
    const int*   corr_index  = (const int*)d_in[7];

    float* out = (float*)d_out;
    float* out_current  = out;                          // [256,1024]   262144
    float* out_pre_act  = out + 262144;                 // [1024]
    float* out_post_act = out + 263168;                 // [1024]
    float* out_avg      = out + 264192;                 // [1024,1024]  1048576
    float* out_hist     = out + 1312768;                // [1024,1024,50]

    float* ws_means = (float*)d_ws;                     // 2048 floats (+pad)
    float* cpart    = ws_means + 4096;                  // 16 KB offset, aligned
    size_t ws_need  = (size_t)4096 * 4 + (size_t)GKSPLIT * BATCH * POST * 4; // 16KB + 8MB
    int use_part    = ws_size >= ws_need;

    means_kernel<<<128, 256, 0, stream>>>(
        pre_spikes, post_spikes, pre_act, post_act,
        ws_means, out_pre_act, out_post_act);

    if (!use_part)
        (void)hipMemsetAsync(out_current, 0, (size_t)BATCH * POST * sizeof(float), stream);

    gemm_kernel<<<dim3(POST / GBN, BATCH / GBM, GKSPLIT), 256, 0, stream>>>(
        pre_spikes, W, Mk, out_current, cpart, use_part);

    if (use_part)
        gemm_reduce_kernel<<<BATCH * POST / 4 / 256, 256, 0, stream>>>(cpart, out_current);

    history_kernel<<<NPAIR / PPB, HTHREADS, 0, stream>>>(
        hist, corr_index, ws_means, out_hist, out_avg);
}

// Round 7
// 370.404 us; speedup vs baseline: 1.1771x; 1.0080x over previous
//
#include <hip/hip_runtime.h>

#define PRE   1024
#define POST  1024
#define BATCH 256
#define HIST  50
#define NPAIR (PRE * POST)

typedef float nf4 __attribute__((ext_vector_type(4)));   // native vec for nontemporal builtins

// ================= fused kernel A: means (blocks 0..127) + gemm (128..639) =================
#define MCOLS 16
#define GBM 64
#define GBN 64
#define GBK 16
#define GKSPLIT 8
#define GLD 68                      // padded leading dim for As/Bs

__global__ __launch_bounds__(256) void fusedA_kernel(
    const float* __restrict__ pre_spikes,   // [BATCH, PRE]  (= gemm A)
    const float* __restrict__ post_spikes,  // [BATCH, POST]
    const float* __restrict__ pre_activity, // [PRE]
    const float* __restrict__ post_activity,// [POST]
    float* __restrict__ ws_means,           // [PRE + POST] scratch
    float* __restrict__ out_pre_act,        // [PRE]
    float* __restrict__ out_post_act,       // [POST]
    const float* __restrict__ W,            // [PRE, POST]
    const float* __restrict__ Mk,           // [PRE, POST]
    float* __restrict__ C,                  // [BATCH, POST] (atomic path)
    float* __restrict__ Cpart,              // [GKSPLIT, BATCH*POST] (partial path)
    int use_part)
{
    int tid = threadIdx.x;

    if (blockIdx.x < 128) {
        // ---------------- means + EMA (R5-proven core) ----------------
        __shared__ float red[256];
        int blk = blockIdx.x;                  // 0..127
        bool is_pre = blk < 64;
        const float* mat = is_pre ? pre_spikes : post_spikes;
        const float* act = is_pre ? pre_activity : post_activity;
        float* out_act   = is_pre ? out_pre_act : out_post_act;
        float* ws        = is_pre ? ws_means : ws_means + PRE;
        int col0 = (blk & 63) * MCOLS;

        int col = col0 + (tid & 15);
        int chunk = tid >> 4;                  // 0..15, 16 rows each
        float s = 0.f;
#pragma unroll
        for (int r = chunk * 16; r < chunk * 16 + 16; ++r)
            s += mat[r * 1024 + col];
        red[tid] = s;
        __syncthreads();
        if (tid < 16) {
            float t = 0.f;
#pragma unroll
            for (int k = 0; k < 16; ++k)
                t += red[k * 16 + tid];
            float m = t * (1.0f / BATCH);
            int c = col0 + tid;
            ws[c] = m;
            out_act[c] = 0.99f * act[c] + 0.01f * m;
        }
        return;
    }

    // ---------------- masked SGEMM 64x64, 4x4/thread, split-K x8 (R6-proven core) ----------------
    __shared__ __align__(16) float As[GBK * GLD];   // As[k][m] (transposed)
    __shared__ __align__(16) float Bs[GBK * GLD];   // Bs[k][n]
    int id = blockIdx.x - 128;     // 0..511
    int bn = id & 15;
    int bm = (id >> 4) & 3;
    int bz = id >> 6;
    int kbase = bz * (PRE / GKSPLIT);

    int ar = tid >> 2;
    int ak = (tid & 3) << 2;
    int bk = tid >> 4;
    int bn4 = (tid & 15) << 2;
    int tn4 = (tid & 15) << 2;
    int tm4 = (tid >> 4) << 2;

    const float* Ap = &pre_spikes[(bm * GBM + ar) * PRE + kbase + ak];
    const float* Wp = &W [(size_t)(kbase + bk) * POST + bn * GBN + bn4];
    const float* Mp = &Mk[(size_t)(kbase + bk) * POST + bn * GBN + bn4];

    float acc[4][4] = {};

    for (int k0 = 0; k0 < PRE / GKSPLIT; k0 += GBK) {
        float4 av = *(const float4*)(Ap + k0);
        float4 wv = *(const float4*)(Wp + (size_t)k0 * POST);
        float4 mv = *(const float4*)(Mp + (size_t)k0 * POST);
        wv.x *= mv.x; wv.y *= mv.y; wv.z *= mv.z; wv.w *= mv.w;
        __syncthreads();                       // protect previous iter's reads
        As[(ak + 0) * GLD + ar] = av.x;
        As[(ak + 1) * GLD + ar] = av.y;
        As[(ak + 2) * GLD + ar] = av.z;
        As[(ak + 3) * GLD + ar] = av.w;
        *(float4*)&Bs[bk * GLD + bn4] = wv;
        __syncthreads();
#pragma unroll
        for (int kk = 0; kk < GBK; ++kk) {
            float4 a4 = *(const float4*)&As[kk * GLD + tm4];
            float4 b4 = *(const float4*)&Bs[kk * GLD + tn4];
            const float* ap = (const float*)&a4;
            const float* bp = (const float*)&b4;
#pragma unroll
            for (int i = 0; i < 4; ++i)
#pragma unroll
                for (int j = 0; j < 4; ++j)
                    acc[i][j] += ap[i] * bp[j];
        }
    }
    if (use_part) {
        float* dst = &Cpart[(size_t)bz * (BATCH * POST)
                            + (size_t)(bm * GBM + tm4) * POST + bn * GBN + tn4];
#pragma unroll
        for (int i = 0; i < 4; ++i) {
            float4 r; r.x = acc[i][0]; r.y = acc[i][1]; r.z = acc[i][2]; r.w = acc[i][3];
            *(float4*)(dst + (size_t)i * POST) = r;
        }
    } else {
#pragma unroll
        for (int i = 0; i < 4; ++i)
#pragma unroll
            for (int j = 0; j < 4; ++j)
                atomicAdd(&C[(size_t)(bm * GBM + tm4 + i) * POST + bn * GBN + tn4 + j],
                          acc[i][j]);
    }
}

// ================= fused kernel B: gemm-reduce (first nred blocks) + history =================
// reduce: C[i] = sum_z Cpart[z][i], float4-vectorized, 205 blocks x 320 thr (guarded).
// history: R5/R6-proven core, blocks nred..nred+8191.
#define PPB 128
#define HTHREADS 320
#define NIT 5                      // 1600 / 320
#define NRED 205                   // ceil(65536 / 320)

__global__ __launch_bounds__(HTHREADS) void fusedB_kernel(
    const float* __restrict__ hist_in,    // [PRE, POST, HIST]
    const int*   __restrict__ corr_index, // scalar
    const float* __restrict__ ws_means,   // [PRE + POST]
    float* __restrict__ hist_out,         // [PRE, POST, HIST]
    float* __restrict__ avg_out,          // [PRE, POST]
    const float* __restrict__ Cpart,      // [GKSPLIT, BATCH*POST]
    float* __restrict__ C,                // [BATCH*POST]
    int nred)
{
    int tid = threadIdx.x;

    if ((int)blockIdx.x < nred) {
        // ---------------- split-K reduce ----------------
        int g = blockIdx.x * HTHREADS + tid;        // float4 index
        if (g < BATCH * POST / 4) {
            const nf4* p4 = (const nf4*)Cpart;
            nf4 s = p4[g];
#pragma unroll
            for (int z = 1; z < GKSPLIT; ++z)
                s += p4[(size_t)z * (BATCH * POST / 4) + g];
            ((nf4*)C)[g] = s;
        }
        return;
    }

    // ---------------- history copy + in-flight scatter + mean ----------------
    __shared__ __align__(16) float tile[PPB * HIST + 2];   // +2: guarded tail over-read
    int p0 = (blockIdx.x - nred) * PPB;
    int idx = ((corr_index[0] % HIST) + HIST) % HIST;

    const nf4* in4   = (const nf4*)(hist_in + (size_t)p0 * HIST);
    nf4*       out4  = (nf4*)(hist_out + (size_t)p0 * HIST);
    nf4*       tile4 = (nf4*)tile;

    nf4 v[NIT];
#pragma unroll
    for (int it = 0; it < NIT; ++it)
        v[it] = __builtin_nontemporal_load(&in4[it * HTHREADS + tid]);

#pragma unroll
    for (int it = 0; it < NIT; ++it) {
        int fl = it * HTHREADS + tid;
        int r0 = 4 * fl;               // relative float index of component 0
        int pl = r0 / HIST;            // local pair of component 0
        int t0 = r0 - pl * HIST;       // slot of component 0 (even, 0..48)
        int d  = idx - t0;             // component holding slot idx (pair pl)
        int d2 = idx + HIST - t0;      // component holding slot idx (pair pl+1), >= 2
        bool needA = ((unsigned)d) < 4u;
        bool needB = (d2 < 4);         // implies t0 == 48; disjoint from needA
        float corr = 0.f;
        if (needA | needB) {           // rare: ~8% of float4s
            int pair = needA ? (p0 + pl) : (p0 + pl + 1);
            corr = ws_means[pair >> 10] * ws_means[PRE + (pair & (POST - 1))];
        }
        nf4 w = v[it];
        w.x = (d == 0) ? corr : w.x;
        w.y = (d == 1) ? corr : w.y;
        w.z = (d == 2 || d2 == 2) ? corr : w.z;
        w.w = (d == 3 || d2 == 3) ? corr : w.w;
        v[it] = w;                     // keep for the post-barrier store
        tile4[fl] = w;
    }
    __syncthreads();                   // only LDS writes outstanding here

#pragma unroll
    for (int it = 0; it < NIT; ++it)
        __builtin_nontemporal_store(v[it], &out4[it * HTHREADS + tid]);

    if (tid < 2 * PPB) {
        int pl   = tid >> 1;
        int half = tid & 1;
        const float2* tp = (const float2*)&tile[pl * HIST];
        float s = 0.f;
#pragma unroll
        for (int k = 0; k < 13; ++k) {         // float2 indices half, half+2, ...
            int f2 = 2 * k + half;
            float2 w = tp[f2];                 // f2==25 over-read lands in pad
            if (f2 < 25) s += w.x + w.y;
        }
        s += __shfl_xor(s, 1);
        if (half == 0)
            __builtin_nontemporal_store(s * (1.0f / HIST), &avg_out[p0 + pl]);
    }
}

extern "C" void kernel_launch(void* const* d_in, const int* in_sizes, int n_in,
                              void* d_out, int out_size, void* d_ws, size_t ws_size,
                              hipStream_t stream)
{
    const float* pre_spikes  = (const float*)d_in[0];
    const float* post_spikes = (const float*)d_in[1];
    const float* W           = (const float*)d_in[2];
    const float* Mk          = (const float*)d_in[3];
    const float* hist        = (const float*)d_in[4];
    const float* pre_act     = (const float*)d_in[5];
    const float* post_act    = (const float*)d_in[6];
    const int*   corr_index  = (const int*)d_in[7];

    float* out = (float*)d_out;
    float* out_current  = out;                          // [256,1024]   262144
    float* out_pre_act  = out + 262144;                 // [1024]
    float* out_post_act = out + 263168;                 // [1024]
    float* out_avg      = out + 264192;                 // [1024,1024]  1048576
    float* out_hist     = out + 1312768;                // [1024,1024,50]

    float* ws_means = (float*)d_ws;                     // 2048 floats (+pad)
    float* cpart    = ws_means + 4096;                  // 16 KB offset, aligned
    size_t ws_need  = (size_t)4096 * 4 + (size_t)GKSPLIT * BATCH * POST * 4; // 16KB + 8MB
    int use_part    = ws_size >= ws_need;

    if (!use_part)
        (void)hipMemsetAsync(out_current, 0, (size_t)BATCH * POST * sizeof(float), stream);

    fusedA_kernel<<<128 + 512, 256, 0, stream>>>(
        pre_spikes, post_spikes, pre_act, post_act,
        ws_means, out_pre_act, out_post_act,
        W, Mk, out_current, cpart, use_part);

    int nred = use_part ? NRED : 0;
    fusedB_kernel<<<nred + NPAIR / PPB, HTHREADS, 0, stream>>>(
        hist, corr_index, ws_means, out_hist, out_avg,
        cpart, out_current, nred);
}